// Round 1
// baseline (239.242 us; speedup 1.0000x reference)
//
#include <hip/hip_runtime.h>

// AR(24) rollout: out[b,t,d] for t in [0,168), from last 24 timesteps of x[b,:,d].
// One thread per (b,d) scalar sequence; window lives in 24 registers.
// Time loop unrolled in groups of ORDER so the sliding window becomes static
// register rotation (no v_mov shift chain). T=168 = 7*24 exactly.

#define BATCH 256
#define SEQ   336
#define DIMS  512
#define ORDER 24
#define TSEQ  168

__global__ __launch_bounds__(256) void ar_rollout_kernel(
    const float* __restrict__ x,     // [BATCH, SEQ, DIMS]
    const float* __restrict__ W,     // [ORDER, 1]
    const float* __restrict__ bias,  // [1]
    float* __restrict__ out)         // [BATCH, TSEQ, DIMS]
{
    const int tid = blockIdx.x * blockDim.x + threadIdx.x;  // b*DIMS + d
    const int d = tid & (DIMS - 1);
    const int b = tid >> 9;          // tid / DIMS
    if (b >= BATCH) return;

    // AR coefficients (wave-uniform -> scalar regs) and bias.
    float wc[ORDER];
#pragma unroll
    for (int k = 0; k < ORDER; ++k) wc[k] = W[k];
    const float bb = bias[0];

    // Init window: x[b, SEQ-ORDER+k, d], k = 0..23 (oldest first).
    // Consecutive lanes = consecutive d -> each of the 24 loads is coalesced.
    const float* xp = x + ((size_t)b * SEQ + (SEQ - ORDER)) * DIMS + d;
    float w[ORDER];
#pragma unroll
    for (int k = 0; k < ORDER; ++k) w[k] = xp[(size_t)k * DIMS];

    // Rollout. At step j within a group, logical window element k lives in
    // physical register w[(j+k) % ORDER]; the new value overwrites w[j].
    float* op = out + (size_t)b * TSEQ * DIMS + d;
#pragma unroll 1
    for (int g = 0; g < TSEQ / ORDER; ++g) {
#pragma unroll
        for (int j = 0; j < ORDER; ++j) {
            float y = bb;
#pragma unroll
            for (int k = 0; k < ORDER; ++k)
                y = fmaf(w[(j + k) % ORDER], wc[k], y);
            w[j] = y;
            *op = y;               // coalesced: lane = d innermost
            op += DIMS;
        }
    }
}

extern "C" void kernel_launch(void* const* d_in, const int* in_sizes, int n_in,
                              void* d_out, int out_size, void* d_ws, size_t ws_size,
                              hipStream_t stream) {
    const float* x    = (const float*)d_in[0];
    const float* W    = (const float*)d_in[1];
    const float* bias = (const float*)d_in[2];
    // d_in[3] is tar_seq_len (==168), compile-time constant here.
    float* out = (float*)d_out;

    const int threads = 256;
    const int blocks  = (BATCH * DIMS) / threads;  // 512
    ar_rollout_kernel<<<blocks, threads, 0, stream>>>(x, W, bias, out);
}